// Round 1
// 552.604 us; speedup vs baseline: 1.0936x; 1.0936x over previous
//
#include <hip/hip_runtime.h>
#include <stdint.h>

// Problem constants (match the reference).
#define B 256
#define K 64
#define L 32
#define SENTINEL 32u
#define NUM_SLOTS 100000
#define HALF 64

// Fused design (R5): one block per batch. Per batch there are at most
// 2*K*L = 4096 walk entries (~2030 distinct node ids for random lens), so the
// per-(batch,node) min-position tables fit in an LDS hash table. This removes
// the 51.2 MB global table entirely: no memset pass, no global atomicCAS RMW
// traffic, no table gather from poison-cold L2/L3. Remaining traffic is the
// structural floor: walk reads (8.4 MB) + output writes (537 MB).
//
// Shared-key open addressing, 4096 slots (max distinct keys == 4096, so the
// table can never overflow; random data sits at ~50% load, ~1.5 probes):
//   s_keys : node id (0 == empty; node 0 is padding and never inserted)
//   s_vsrc : min position of node in src walks (init SENTINEL)
//   s_vtgt : min position of node in tgt walks (init SENTINEL)
// Cross-perspective lookups always terminate because keys are shared: any
// valid node queried from either side was inserted by at least one side; the
// absent side's value stays SENTINEL, matching the reference table init.

#define HASH_SIZE 4096
#define HASH_MASK 4095u
#define THREADS 1024

typedef float fvec4 __attribute__((ext_vector_type(4)));

__global__ __launch_bounds__(THREADS) void wpe_fused_kernel(
    const int* __restrict__ src_walks,
    const int* __restrict__ tgt_walks,
    const int* __restrict__ src_lens,
    const int* __restrict__ tgt_lens,
    const float* __restrict__ own_emb,
    const float* __restrict__ cross_emb,
    fvec4* __restrict__ out) {
  __shared__ int          s_keys[HASH_SIZE];
  __shared__ unsigned int s_vsrc[HASH_SIZE];
  __shared__ unsigned int s_vtgt[HASH_SIZE];
  __shared__ int          s_lens[2 * K];

  const unsigned int b = blockIdx.x;
  const unsigned int t = threadIdx.x;
  const unsigned int base = b * (K * L);  // flat (b,0,0) index into walks

  // ---- Phase 0: init hash + stage lens -------------------------------------
  for (unsigned int i = t; i < HASH_SIZE; i += THREADS) {
    s_keys[i] = 0;
    s_vsrc[i] = SENTINEL;
    s_vtgt[i] = SENTINEL;
  }
  if (t < 2 * K) {
    s_lens[t] = (t < K) ? src_lens[b * K + t] : tgt_lens[b * K + (t - K)];
  }
  __syncthreads();

  // ---- Phase 1: scatter-min into LDS hash ----------------------------------
  // e in [0, 4096): which = e>>11, idx = e & 2047 (k = idx>>5, l = idx&31).
  for (unsigned int e = t; e < 2u * K * L; e += THREADS) {
    unsigned int which = e >> 11;
    unsigned int idx   = e & 2047u;
    unsigned int l     = idx & (L - 1);
    unsigned int k     = idx >> 5;
    const int* walks = which ? tgt_walks : src_walks;
    int node = walks[base + idx];
    int len  = s_lens[which * K + k];
    if ((int)l < len && node != 0) {
      unsigned int h = ((unsigned int)node * 0x9E3779B1u) >> 20;  // top 12 bits
      while (true) {
        int prev = atomicCAS(&s_keys[h], 0, node);
        if (prev == 0 || prev == node) break;
        h = (h + 1) & HASH_MASK;
      }
      if (which) atomicMin(&s_vtgt[h], l);
      else       atomicMin(&s_vsrc[h], l);
    }
  }
  __syncthreads();

  // ---- Phase 2: gather + embed + write -------------------------------------
  // 4096 rows x 128 floats. 8 lanes per row, lane c writes four float4s:
  // own[c], own[c+8], cross[c], cross[c+8]. Each 8-lane group's stores form
  // contiguous 128 B segments (full cache lines, no RFO).
  const unsigned int c    = t & 7u;
  const unsigned int rsub = t >> 3;  // 0..127 rows per pass
  for (unsigned int pass = 0; pass < 32; ++pass) {
    unsigned int e     = pass * 128u + rsub;  // 0..4095
    unsigned int which = e >> 11;
    unsigned int idx   = e & 2047u;
    unsigned int l     = idx & (L - 1);
    unsigned int k     = idx >> 5;
    const int* walks = which ? tgt_walks : src_walks;
    int node = walks[base + idx];         // 8 lanes broadcast-read same word
    int len  = s_lens[which * K + k];

    fvec4 vo0, vo1, vc0, vc1;
    if ((int)l < len && node != 0) {
      unsigned int h = ((unsigned int)node * 0x9E3779B1u) >> 20;
      while (s_keys[h] != node) h = (h + 1) & HASH_MASK;  // key guaranteed present
      unsigned int ps = s_vsrc[h];
      unsigned int pt = s_vtgt[h];
      unsigned int pown   = which ? pt : ps;
      unsigned int pcross = which ? ps : pt;
      const fvec4* eo = (const fvec4*)(own_emb   + pown   * HALF);
      const fvec4* ec = (const fvec4*)(cross_emb + pcross * HALF);
      vo0 = eo[c];
      vo1 = eo[c + 8u];
      vc0 = ec[c];
      vc1 = ec[c + 8u];
    } else {
      vo0 = vo1 = vc0 = vc1 = (fvec4)(0.f, 0.f, 0.f, 0.f);
    }
    unsigned int row  = which * (unsigned int)(B * K * L) + base + idx;
    unsigned int ob   = row * 32u;
    out[ob + c]       = vo0;
    out[ob + 8u + c]  = vo1;
    out[ob + 16u + c] = vc0;
    out[ob + 24u + c] = vc1;
  }
}

// ---------------------------------------------------------------------------
extern "C" void kernel_launch(void* const* d_in, const int* in_sizes, int n_in,
                              void* d_out, int out_size, void* d_ws, size_t ws_size,
                              hipStream_t stream) {
  const int*   src_walks = (const int*)d_in[0];
  const int*   tgt_walks = (const int*)d_in[1];
  const int*   src_lens  = (const int*)d_in[2];
  const int*   tgt_lens  = (const int*)d_in[3];
  const float* own_emb   = (const float*)d_in[4];
  const float* cross_emb = (const float*)d_in[5];

  // One block per batch; hash + gather fully fused, no workspace needed.
  wpe_fused_kernel<<<B, THREADS, 0, stream>>>(
      src_walks, tgt_walks, src_lens, tgt_lens, own_emb, cross_emb,
      (fvec4*)d_out);
}

// Round 2
// 539.741 us; speedup vs baseline: 1.1197x; 1.0238x over previous
//
#include <hip/hip_runtime.h>
#include <stdint.h>

// Problem constants (match the reference).
#define B 256
#define K 64
#define L 32
#define SENTINEL 32u
#define NUM_SLOTS 100000
#define HALF 64

// R6: split the fused kernel (R5, ~200 us of GPU time) into resolve + expand.
// R5's single kernel ran 256 blocks = 1 block/CU, 4 waves/SIMD: the
// store-bound phase 2 (537 MB) was concurrency-starved behind the phase-1
// barrier. Here:
//   Kernel 1 (resolve): thin grid, builds the per-batch LDS hash (unchanged
//     from R5) and resolves every walk element to a packed u16
//     (pown | pcross<<6, 0xFFFF = invalid) -> 2 MB stream to d_ws.
//   Kernel 2 (expand): 8.4M threads, no LDS, minimal VGPRs, full occupancy.
//     Broadcast-reads the u16 code per row, gathers from the L1-resident
//     embedding tables (8.4 KB each), writes 537 MB in 128 B-contiguous
//     segments. Pure store-roofline kernel.

#define HASH_SIZE 4096
#define HASH_MASK 4095u
#define THREADS 1024
#define ROWS (2 * B * K * L)          // 1,048,576 output rows
#define ROWS_PER_BATCH (2 * K * L)    // 4096

typedef float fvec4 __attribute__((ext_vector_type(4)));

// ---------------------------------------------------------------------------
// Kernel 1: hash build + per-element position resolve.
// ---------------------------------------------------------------------------
__global__ __launch_bounds__(THREADS) void wpe_resolve_kernel(
    const int* __restrict__ src_walks,
    const int* __restrict__ tgt_walks,
    const int* __restrict__ src_lens,
    const int* __restrict__ tgt_lens,
    unsigned short* __restrict__ codes) {
  __shared__ int          s_keys[HASH_SIZE];
  __shared__ unsigned int s_vsrc[HASH_SIZE];
  __shared__ unsigned int s_vtgt[HASH_SIZE];
  __shared__ int          s_lens[2 * K];

  const unsigned int b = blockIdx.x;
  const unsigned int t = threadIdx.x;
  const unsigned int base = b * (K * L);

  // ---- Phase 0: init hash + stage lens ----
  for (unsigned int i = t; i < HASH_SIZE; i += THREADS) {
    s_keys[i] = 0;
    s_vsrc[i] = SENTINEL;
    s_vtgt[i] = SENTINEL;
  }
  if (t < 2 * K) {
    s_lens[t] = (t < K) ? src_lens[b * K + t] : tgt_lens[b * K + (t - K)];
  }
  __syncthreads();

  // ---- Phase 1: scatter-min into LDS hash ----
  for (unsigned int e = t; e < ROWS_PER_BATCH; e += THREADS) {
    unsigned int which = e >> 11;
    unsigned int idx   = e & 2047u;
    unsigned int l     = idx & (L - 1);
    unsigned int k     = idx >> 5;
    const int* walks = which ? tgt_walks : src_walks;
    int node = walks[base + idx];
    int len  = s_lens[which * K + k];
    if ((int)l < len && node != 0) {
      unsigned int h = ((unsigned int)node * 0x9E3779B1u) >> 20;
      while (true) {
        int prev = atomicCAS(&s_keys[h], 0, node);
        if (prev == 0 || prev == node) break;
        h = (h + 1) & HASH_MASK;
      }
      if (which) atomicMin(&s_vtgt[h], l);
      else       atomicMin(&s_vsrc[h], l);
    }
  }
  __syncthreads();

  // ---- Phase 2: resolve every element to a packed u16 code ----
  // code = pown | pcross<<6 ; 0xFFFF = invalid (emit zeros downstream).
  for (unsigned int e = t; e < ROWS_PER_BATCH; e += THREADS) {
    unsigned int which = e >> 11;
    unsigned int idx   = e & 2047u;
    unsigned int l     = idx & (L - 1);
    unsigned int k     = idx >> 5;
    const int* walks = which ? tgt_walks : src_walks;
    int node = walks[base + idx];
    int len  = s_lens[which * K + k];
    unsigned short code = 0xFFFFu;
    if ((int)l < len && node != 0) {
      unsigned int h = ((unsigned int)node * 0x9E3779B1u) >> 20;
      while (s_keys[h] != node) h = (h + 1) & HASH_MASK;  // key guaranteed present
      unsigned int ps = s_vsrc[h];
      unsigned int pt = s_vtgt[h];
      unsigned int pown   = which ? pt : ps;
      unsigned int pcross = which ? ps : pt;
      code = (unsigned short)(pown | (pcross << 6));
    }
    codes[which * (unsigned)(B * K * L) + base + idx] = code;
  }
}

// ---------------------------------------------------------------------------
// Kernel 2: expand codes -> embeddings. 8 lanes per 128-float row; lane c
// writes own[c], own[c+8], cross[c], cross[c+8] (four float4 stores; each
// 8-lane group's stores are contiguous 128 B segments -> full lines, no RFO).
// ---------------------------------------------------------------------------
__global__ __launch_bounds__(256) void wpe_expand_kernel(
    const unsigned short* __restrict__ codes,
    const float* __restrict__ own_emb,
    const float* __restrict__ cross_emb,
    fvec4* __restrict__ out) {
  unsigned int tid = blockIdx.x * blockDim.x + threadIdx.x;  // < 2^23
  unsigned int row = tid >> 3;
  unsigned int c   = tid & 7u;

  unsigned int code = codes[row];  // 8 lanes broadcast-read the same u16

  fvec4 vo0, vo1, vc0, vc1;
  if (code != 0xFFFFu) {
    unsigned int pown   = code & 63u;
    unsigned int pcross = (code >> 6) & 63u;
    const fvec4* eo = (const fvec4*)(own_emb   + pown   * HALF);
    const fvec4* ec = (const fvec4*)(cross_emb + pcross * HALF);
    vo0 = eo[c];
    vo1 = eo[c + 8u];
    vc0 = ec[c];
    vc1 = ec[c + 8u];
  } else {
    vo0 = vo1 = vc0 = vc1 = (fvec4)(0.f, 0.f, 0.f, 0.f);
  }
  unsigned int ob = row * 32u;
  out[ob + c]       = vo0;
  out[ob + 8u + c]  = vo1;
  out[ob + 16u + c] = vc0;
  out[ob + 24u + c] = vc1;
}

// ---------------------------------------------------------------------------
extern "C" void kernel_launch(void* const* d_in, const int* in_sizes, int n_in,
                              void* d_out, int out_size, void* d_ws, size_t ws_size,
                              hipStream_t stream) {
  const int*   src_walks = (const int*)d_in[0];
  const int*   tgt_walks = (const int*)d_in[1];
  const int*   src_lens  = (const int*)d_in[2];
  const int*   tgt_lens  = (const int*)d_in[3];
  const float* own_emb   = (const float*)d_in[4];
  const float* cross_emb = (const float*)d_in[5];

  unsigned short* codes = (unsigned short*)d_ws;  // 2 MB

  // Step 1: per-batch hash build + element resolve (thin grid, LDS-heavy).
  wpe_resolve_kernel<<<B, THREADS, 0, stream>>>(
      src_walks, tgt_walks, src_lens, tgt_lens, codes);

  // Step 2: streaming expand (full occupancy, store-roofline).
  {
    const unsigned int total = ROWS * 8u;  // 8,388,608 threads
    wpe_expand_kernel<<<total / 256, 256, 0, stream>>>(
        codes, own_emb, cross_emb, (fvec4*)d_out);
  }
}